// Round 13
// baseline (358.459 us; speedup 1.0000x reference)
//
#include <hip/hip_runtime.h>
#include <math.h>

// PhaseNN on MI355X.  ROUND 24: T2 -> i4, ENTIRELY LDS-resident (zero global
// T2 stream; global/eval 240 -> 128 KB = T1 only).
// R23 post-mortem: i4-T1 bought 50 us at unchanged absmax (stream model
// confirmed: ~0.39 us/eval per 128 KB).  R24 applies the same transform to T2:
//  - i4 frag-pair = [cos 8B | sin 8B]/lane = 1024 B -> all 64 ct tiles = 128 KB
//    fit in LDS (138 KB total).  Waves all read LDS in GEMM2; wsb T2 region
//    unused.
//  - GEMM2 bias does NOT cancel (no softmax downstream): aC_raw = 7*Sum(cw) +
//    8*Sw with Sw = Sum_p w^i8_p.  Softmax wave computes Sw exactly (integer
//    shuffle-reduce, 1 extra LDS int) and GEMM2 subtracts 8*Sw -> the ONLY new
//    error is i4 table quantization on the coupling (~0.013 weighted-avg,
//    integrated ~0.007).  Expected absmax ~0.02; fail => revert T2 to i8.
//  - kscale = 1/(7*127) = 1/889.
// Tripwire: WRITE > 4 MB = spill -> revert.
// Structure: 256 blocks x 1 row, 16 waves, i8-MFMA K=64 (i4 operands biased),
// 3 barriers/eval, T1 global i4 128K.

typedef __attribute__((ext_vector_type(4))) float f32x4;
typedef __attribute__((ext_vector_type(4))) int   i32x4;
typedef __attribute__((ext_vector_type(8))) short bf16x8;

struct TCons { float s[64]; float c[64]; };

__device__ __forceinline__ unsigned short f2bf(float f) {
  unsigned u = __builtin_bit_cast(unsigned, f);
  return (unsigned short)((u + 0x7FFFu + ((u >> 16) & 1u)) >> 16);
}

#define A1_OFF    0        // feats: GEMM1 i8 [cos 1024 | sin 1024]; epilogue bf16 [cos 2048 | sin 2048]
#define MBUF_OFF  4096     // m partials i32: 2 kh x 132 (kh stride 528) = 1056
#define W_OFF     5152     // w i8 (x127): 128 B + Sw (int) @ +128
#define ZP_OFF    5408     // 16 B zero page (bf16 epilogue pad cols)
#define XST_OFF   5424     // 104 chunks x 16 B bf16 (encoder prologue only)
#define T2L_OFF   7104     // T2 i4: 128 frag-pairs x 1024 B = 131072
#define RED_OFF   7104     // epilogue overlay (T2L dead by then): 16 KiB
#define LDS_BYTES 138176   // ~135 KiB of 160 KiB

__global__
__attribute__((amdgpu_flat_work_group_size(1024, 1024), amdgpu_waves_per_eu(4, 4)))
void phasenn_kernel(
    const float* __restrict__ x, const float* __restrict__ W_enc,
    const float* __restrict__ b_enc, const float* __restrict__ xi,
    const float* __restrict__ W_out, const float* __restrict__ b_out,
    float* __restrict__ dout, char* __restrict__ wsb, TCons tc)
{
  __shared__ __align__(16) char smem[LDS_BYTES];

  const int tid  = threadIdx.x;
  const int bk   = blockIdx.x;        // batch row bk
  const int w    = tid >> 6;          // 16 waves
  const int lane = tid & 63;
  const int q    = lane >> 4;
  const int b16  = lane & 15;         // MFMA col slot (batch row duplicated x16)
  const int j4   = b16 >> 2;          // lane's n-subtile j / GEMM2 ct select
  const int r4   = b16 & 3;           // lane's r within the D reg quad
  const int nph  = (w*4 + j4)*16 + q*4 + r4;   // the ONE phase this lane owns

  char* T1g = wsb;                    // 128 KiB: (pt 8, F 16) i4 frags x 64 lanes x 16 B

  // ---- LDS init: zero page only
  if (tid < 4) *(unsigned*)(smem + ZP_OFF + tid*4) = 0;

  // ---- xstage: x row bk -> bf16 B-frag chunks (linear), d>=784 zero (encoder)
  if (tid < 100) {
    const int dg = tid;
    bf16x8 fr = {0,0,0,0,0,0,0,0};
    if (dg < 98) {
      f32x4 v0 = *(const f32x4*)(x + (size_t)bk*784 + dg*8);
      f32x4 v1 = *(const f32x4*)(x + (size_t)bk*784 + dg*8 + 4);
      #pragma unroll
      for (int i = 0; i < 8; ++i) fr[i] = (short)f2bf(i < 4 ? v0[i] : v1[i-4]);
    }
    *(bf16x8*)(smem + XST_OFF + (dg << 4)) = fr;
  }

  // ---- table gen: both tables i4 biased +8 (u = round(v*7)+8 in [1,15])
  if (w < 8) {  // T1 -> global: lane: p = w*16+b16, n = F*64 + q*16 + i
    const int p = w*16 + b16;
    for (int F = 0; F < 16; ++F) {
      const int n0 = F*64 + q*16;
      f32x4 v0 = *(const f32x4*)(xi + p*1024 + n0);
      f32x4 v1 = *(const f32x4*)(xi + p*1024 + n0 + 4);
      f32x4 v2 = *(const f32x4*)(xi + p*1024 + n0 + 8);
      f32x4 v3 = *(const f32x4*)(xi + p*1024 + n0 + 12);
      int cu[16], su[16];
      #pragma unroll
      for (int i = 0; i < 16; ++i) {
        float xv = (i < 4) ? v0[i] : (i < 8) ? v1[i-4] : (i < 12) ? v2[i-8] : v3[i-12];
        su[i] = __float2int_rn(__sinf(xv)*7.0f) + 8;   // 1..15
        cu[i] = __float2int_rn(__cosf(xv)*7.0f) + 8;
      }
      unsigned pc0=0, pc1=0, ps0=0, ps1=0;
      #pragma unroll
      for (int i = 0; i < 4; ++i) {
        pc0 |= (unsigned)(cu[i]     | (cu[i+4]  << 4)) << (8*i);
        pc1 |= (unsigned)(cu[8+i]   | (cu[12+i] << 4)) << (8*i);
        ps0 |= (unsigned)(su[i]     | (su[i+4]  << 4)) << (8*i);
        ps1 |= (unsigned)(su[8+i]   | (su[12+i] << 4)) << (8*i);
      }
      i32x4 P = {(int)pc0, (int)pc1, (int)ps0, (int)ps1};
      *(i32x4*)(T1g + (size_t)(w*16 + F)*1024 + lane*16) = P;
    }
  } else {      // T2 -> LDS: lane: n = ct*16+b16, p = P2*64 + q*16 + i
    const int w2 = w - 8;
    for (int f = 0; f < 16; ++f) {
      const int ct = w2*8 + (f >> 1), P2 = f & 1;
      const int n = ct*16 + b16;
      int cu[16], su[16];
      #pragma unroll
      for (int i = 0; i < 16; ++i) {
        float xv = xi[(P2*64 + q*16 + i)*1024 + n];
        su[i] = __float2int_rn(__sinf(xv)*7.0f) + 8;
        cu[i] = __float2int_rn(__cosf(xv)*7.0f) + 8;
      }
      unsigned pc0=0, pc1=0, ps0=0, ps1=0;
      #pragma unroll
      for (int i = 0; i < 4; ++i) {
        pc0 |= (unsigned)(cu[i]     | (cu[i+4]  << 4)) << (8*i);
        pc1 |= (unsigned)(cu[8+i]   | (cu[12+i] << 4)) << (8*i);
        ps0 |= (unsigned)(su[i]     | (su[i+4]  << 4)) << (8*i);
        ps1 |= (unsigned)(su[8+i]   | (su[12+i] << 4)) << (8*i);
      }
      i32x4 P = {(int)pc0, (int)pc1, (int)ps0, (int)ps1};
      *(i32x4*)(smem + T2L_OFF + (size_t)(ct*2 + P2)*1024 + lane*16) = P;
    }
  }
  __syncthreads();

  // ---- encoder (bf16 MFMA): B cols all duplicate row bk; lane keeps 1 phase.
  float p0, ka, pwv;
  {
    f32x4 pac[4] = {{0,0,0,0},{0,0,0,0},{0,0,0,0},{0,0,0,0}};
    for (int kt = 0; kt < 25; ++kt) {
      bf16x8 bfr = *(const bf16x8*)(smem + XST_OFF + ((kt*4 + q) << 4));
      const int d = kt*32 + q*8;
      #pragma unroll
      for (int j = 0; j < 4; ++j) {
        bf16x8 afr = {0,0,0,0,0,0,0,0};
        if (d < 784) {
          const int n = (w*4 + j)*16 + b16;
          f32x4 v0 = *(const f32x4*)(W_enc + n*784 + d);
          f32x4 v1 = *(const f32x4*)(W_enc + n*784 + d + 4);
          #pragma unroll
          for (int i = 0; i < 8; ++i) afr[i] = (short)f2bf(i < 4 ? v0[i] : v1[i-4]);
        }
        pac[j] = __builtin_amdgcn_mfma_f32_16x16x32_bf16(afr, bfr, pac[j], 0, 0, 0);
      }
    }
    f32x4 pc = (j4==0) ? pac[0] : (j4==1) ? pac[1] : (j4==2) ? pac[2] : pac[3];
    float vA = (r4==0) ? pc[0] : (r4==1) ? pc[1] : (r4==2) ? pc[2] : pc[3];
    float ph = 6.283185307179586f / (1.0f + __expf(-(vA + b_enc[nph])));
    p0 = ph; pwv = ph; ka = 0.0f;
  }

  const float dtf = 0.03125f, half = 0.015625f;
  const float sixth = (float)(0.03125/6.0);
  const float mscale = (float)(2.0 / (1024.0 * 889.0));     // BETA/N / (7*127)
  const float kscale = (float)(1.0 / 889.0);                // 1/(7*127)

  char* a1wr = smem + A1_OFF + nph;   // per-lane feat byte address (constant)

  for (int e = 0; e < 64; ++e) {
    float csv, snv;
    // ---- Phase A: all 64 lanes, 1 phase each; 1 cos + 1 sin byte store
    {
      snv = __sinf(pwv);
      csv = __cosf(pwv);
      *(char*)(a1wr)        = (char)(__float2int_rn(csv*127.0f));
      *(char*)(a1wr + 1024) = (char)(__float2int_rn(snv*127.0f));
    }
    __syncthreads();

    // ---- GEMM1 i8 K=64 with i4 T1 (unpack = AND/SHR, biased +8); 16 MFMA/wave
    {
      const int pt = w & 7, kh = w >> 3;
      i32x4 accC = {0,0,0,0}, accS = {0,0,0,0};
      const char* t1b = T1g + (size_t)(pt*16 + kh*8)*1024 + lane*16;
      const char* a1b = smem + A1_OFF + kh*512 + q*16;
      const unsigned M = 0x0F0F0F0Fu;
      #pragma unroll
      for (int i2 = 0; i2 < 8; ++i2) {
        i32x4 pk = *(const i32x4*)(t1b + (size_t)i2*1024);
        i32x4 ca = { (int)((unsigned)pk[0] & M), (int)(((unsigned)pk[0] >> 4) & M),
                     (int)((unsigned)pk[1] & M), (int)(((unsigned)pk[1] >> 4) & M) };
        i32x4 sa = { (int)((unsigned)pk[2] & M), (int)(((unsigned)pk[2] >> 4) & M),
                     (int)((unsigned)pk[3] & M), (int)(((unsigned)pk[3] >> 4) & M) };
        i32x4 bc = *(const i32x4*)(a1b + i2*64);
        i32x4 bs = *(const i32x4*)(a1b + i2*64 + 1024);
        accC = __builtin_amdgcn_mfma_i32_16x16x64_i8(ca, bc, accC, 0, 0, 0);
        accS = __builtin_amdgcn_mfma_i32_16x16x64_i8(sa, bs, accS, 0, 0, 0);
      }
      if (b16 == 0) {
        i32x4 acc = accC + accS;
        *(i32x4*)(smem + MBUF_OFF + kh*528 + ((pt*16 + q*4) << 2)) = acc;
      }
    }
    __syncthreads();

    // ---- softmax (wave 0): shift-invariant to T1 bias; w i8 (x127) + exact
    // integer Sw = Sum_p w^i8_p for GEMM2 bias correction.
    if (w == 0) {
      const char* mb = smem + MBUF_OFF + lane*8;
      int a0 = *(const int*)(mb),       a1 = *(const int*)(mb + 4);
      int b0 = *(const int*)(mb + 528), b1 = *(const int*)(mb + 528 + 4);
      float e0 = __expf((float)(a0 + b0) * mscale);
      float e1 = __expf((float)(a1 + b1) * mscale);
      float s = e0 + e1;
      #pragma unroll
      for (int off = 1; off < 64; off <<= 1) s += __shfl_xor(s, off, 64);
      const float inv = 127.0f / s;
      int w0 = __float2int_rn(e0 * inv);
      int w1 = __float2int_rn(e1 * inv);
      *(unsigned short*)(smem + W_OFF + lane*2) =
          (unsigned short)((w0 & 255) | (w1 << 8));
      int sw = w0 + w1;
      #pragma unroll
      for (int off = 1; off < 64; off <<= 1) sw += __shfl_xor(sw, off, 64);
      if (lane == 0) *(int*)(smem + W_OFF + 128) = sw;
    }
    __syncthreads();

    // ---- GEMM2 (i4 T2 from LDS, all waves) + RK4: 16 MFMA/wave; bias 8*Sw
    // subtracted exactly; cached trig.
    {
      const float swt = tc.s[e], cwt = tc.c[e];
      const int st = e & 3;
      i32x4 wf0 = *(const i32x4*)(smem + W_OFF + q*16);
      i32x4 wf1 = *(const i32x4*)(smem + W_OFF + 64 + q*16);
      const int bias8 = 8 * (*(const int*)(smem + W_OFF + 128));
      i32x4 aC[4] = {{0,0,0,0},{0,0,0,0},{0,0,0,0},{0,0,0,0}};
      i32x4 aS[4] = {{0,0,0,0},{0,0,0,0},{0,0,0,0},{0,0,0,0}};
      const char* t2b = smem + T2L_OFF + (size_t)(w*8)*1024 + lane*16;
      const unsigned M = 0x0F0F0F0Fu;
      #pragma unroll
      for (int c = 0; c < 4; ++c)
        #pragma unroll
        for (int P2 = 0; P2 < 2; ++P2) {
          i32x4 pk = *(const i32x4*)(t2b + (size_t)(c*2 + P2)*1024);
          i32x4 ct_ = { (int)((unsigned)pk[0] & M), (int)(((unsigned)pk[0] >> 4) & M),
                        (int)((unsigned)pk[1] & M), (int)(((unsigned)pk[1] >> 4) & M) };
          i32x4 st_ = { (int)((unsigned)pk[2] & M), (int)(((unsigned)pk[2] >> 4) & M),
                        (int)((unsigned)pk[3] & M), (int)(((unsigned)pk[3] >> 4) & M) };
          i32x4 wf = P2 ? wf1 : wf0;
          aC[c] = __builtin_amdgcn_mfma_i32_16x16x64_i8(ct_, wf, aC[c], 0, 0, 0);
          aS[c] = __builtin_amdgcn_mfma_i32_16x16x64_i8(st_, wf, aS[c], 0, 0, 0);
        }
      i32x4 c4 = (j4==0) ? aC[0] : (j4==1) ? aC[1] : (j4==2) ? aC[2] : aC[3];
      i32x4 s4 = (j4==0) ? aS[0] : (j4==1) ? aS[1] : (j4==2) ? aS[2] : aS[3];
      int iC = (r4==0) ? c4[0] : (r4==1) ? c4[1] : (r4==2) ? c4[2] : c4[3];
      int iS = (r4==0) ? s4[0] : (r4==1) ? s4[1] : (r4==2) ? s4[2] : s4[3];
      float vC = (float)(iC - bias8);
      float vS = (float)(iS - bias8);
      float kv = (snv*vC - csv*vS) * kscale
               + 0.08f*(swt*csv - cwt*snv);           // A*sin(wt - phi)
      if (st == 0)      { ka  = kv;           pwv = p0 + kv*half; }
      else if (st == 1) { ka += 2.0f*kv;      pwv = p0 + kv*half; }
      else if (st == 2) { ka += 2.0f*kv;      pwv = p0 + kv*dtf;  }
      else { ka += kv; p0 += ka*sixth; pwv = p0; }
    }
  }

  // ---- epilogue (bf16 MFMA): out = [cos phiT, sin phiT] @ W_out^T + b_out
  __syncthreads();
  {
    *(unsigned short*)(smem + A1_OFF + nph*2)        = f2bf(__cosf(p0));
    *(unsigned short*)(smem + A1_OFF + 2048 + nph*2) = f2bf(__sinf(p0));
  }
  __syncthreads();
  {  // D[cl][col] partial over this wave's 4 ktiles; A = W_out rows (cl<10, pad 0)
    f32x4 acc = {0.f, 0.f, 0.f, 0.f};
    #pragma unroll
    for (int i2 = 0; i2 < 4; ++i2) {
      const int kt = w*4 + i2;
      const int k = kt*32 + q*8;
      bf16x8 afr = {0,0,0,0,0,0,0,0};
      if (b16 < 10) {
        f32x4 v0 = *(const f32x4*)(W_out + b16*2048 + k);
        f32x4 v1 = *(const f32x4*)(W_out + b16*2048 + k + 4);
        #pragma unroll
        for (int i = 0; i < 8; ++i) afr[i] = (short)f2bf(i < 4 ? v0[i] : v1[i-4]);
      }
      const char* baddr = (b16 == 0)
          ? (smem + A1_OFF + ((kt*4 + q) << 4))
          : (smem + ZP_OFF);
      bf16x8 bfr = *(const bf16x8*)baddr;
      acc = __builtin_amdgcn_mfma_f32_16x16x32_bf16(afr, bfr, acc, 0, 0, 0);
    }
    *(f32x4*)(smem + RED_OFF + ((w*64 + lane) << 4)) = acc;
  }
  __syncthreads();
  if (tid < 64) {   // reduce 16 wave-partials; lane: col = tid&15, cl = (tid>>4)*4+r
    f32x4 s = {0.f, 0.f, 0.f, 0.f};
    #pragma unroll
    for (int w2 = 0; w2 < 16; ++w2)
      s += *(const f32x4*)(smem + RED_OFF + ((w2*64 + tid) << 4));
    const int b = tid & 15, q2 = tid >> 4;
    if (b == 0) {
      #pragma unroll
      for (int r = 0; r < 4; ++r) {
        const int cl = q2*4 + r;
        if (cl < 10)
          dout[(size_t)bk*10 + cl] = s[r] + b_out[cl];
      }
    }
  }
}

extern "C" void kernel_launch(void* const* d_in, const int* in_sizes, int n_in,
                              void* d_out, int out_size, void* d_ws, size_t ws_size,
                              hipStream_t stream) {
  (void)in_sizes; (void)n_in; (void)ws_size; (void)out_size;
  const float* x     = (const float*)d_in[0];
  const float* W_enc = (const float*)d_in[1];
  const float* b_enc = (const float*)d_in[2];
  const float* xi    = (const float*)d_in[3];
  const float* W_out = (const float*)d_in[4];
  const float* b_out = (const float*)d_in[5];
  float* out = (float*)d_out;
  char* wsb = (char*)d_ws;   // T1 i4 128K @0; rewritten per launch (T2 now LDS-only)

  TCons tc;
  const double OME = 2.0 * 3.14159265358979323846 * 200.0;
  const double dtd = 0.03125;
  const double co[4] = {0.0, 0.5, 0.5, 1.0};
  for (int e = 0; e < 64; ++e) {
    double t = ((double)(e >> 2) + co[e & 3]) * dtd;
    tc.s[e] = (float)sin(OME * t);
    tc.c[e] = (float)cos(OME * t);
  }

  phasenn_kernel<<<dim3(256), dim3(1024), 0, stream>>>(
      x, W_enc, b_enc, xi, W_out, b_out, out, wsb, tc);
}

// Round 14
// 355.418 us; speedup vs baseline: 1.0086x; 1.0086x over previous
//
#include <hip/hip_runtime.h>
#include <math.h>

// PhaseNN on MI355X.  ROUND 25: T1 -> i2 (global stream 128 -> 64 KB/eval).
// R24 post-mortem: removing T2g (112 KB, 7 waves) was NEUTRAL -- offset by
// +96 unpack ops in all 16 waves; but R23's -50 us for -128 KB of T1 (ALL
// waves, ~58 B/cyc) shows the UNIFORM T1 stream is the binding memory term.
// Softmax args are ~+-0.03 (m ~ sqrtN * BETA/N) -> w nearly uniform -> T1
// precision nearly free (i4 changed absmax by exactly 0).
// R25: T1 i2, levels {-1,-1/3,1/3,1} via u = rn(1.5c+1.5) in [0,3]; bias
// 1.5*Sum(f) is p-independent -> softmax shift-invariant.  Frag-pair = 8 B/lane
// (cos dword | sin dword); pack pos(i) = 8*(i&3)+2*(i>>2) so SWAR unpack is
// out_j = (p>>2j) & 0x03030303 (7 ops/plane).  mscale = BETA/N/(1.5*127).
// Predicted: -64 KB x ~17.5 cyc/KB ~= -26 us.  absmax <= 0.02 else revert.
// Tripwire: WRITE > 4 MB = spill.
// Structure: 256 blocks x 1 row, 16 waves, i8-MFMA K=64, 3 barriers/eval,
// T1 global i2 64K; T2 i4 LDS-resident (128K).

typedef __attribute__((ext_vector_type(4))) float f32x4;
typedef __attribute__((ext_vector_type(4))) int   i32x4;
typedef __attribute__((ext_vector_type(2))) int   i32x2;
typedef __attribute__((ext_vector_type(8))) short bf16x8;

struct TCons { float s[64]; float c[64]; };

__device__ __forceinline__ unsigned short f2bf(float f) {
  unsigned u = __builtin_bit_cast(unsigned, f);
  return (unsigned short)((u + 0x7FFFu + ((u >> 16) & 1u)) >> 16);
}

#define A1_OFF    0        // feats: GEMM1 i8 [cos 1024 | sin 1024]; epilogue bf16 [cos 2048 | sin 2048]
#define MBUF_OFF  4096     // m partials i32: 2 kh x 132 (kh stride 528) = 1056
#define W_OFF     5152     // w i8 (x127): 128 B + Sw (int) @ +128
#define ZP_OFF    5408     // 16 B zero page (bf16 epilogue pad cols)
#define XST_OFF   5424     // 104 chunks x 16 B bf16 (encoder prologue only)
#define T2L_OFF   7104     // T2 i4: 128 frag-pairs x 1024 B = 131072
#define RED_OFF   7104     // epilogue overlay (T2L dead by then): 16 KiB
#define LDS_BYTES 138176   // ~135 KiB of 160 KiB

__global__
__attribute__((amdgpu_flat_work_group_size(1024, 1024), amdgpu_waves_per_eu(4, 4)))
void phasenn_kernel(
    const float* __restrict__ x, const float* __restrict__ W_enc,
    const float* __restrict__ b_enc, const float* __restrict__ xi,
    const float* __restrict__ W_out, const float* __restrict__ b_out,
    float* __restrict__ dout, char* __restrict__ wsb, TCons tc)
{
  __shared__ __align__(16) char smem[LDS_BYTES];

  const int tid  = threadIdx.x;
  const int bk   = blockIdx.x;        // batch row bk
  const int w    = tid >> 6;          // 16 waves
  const int lane = tid & 63;
  const int q    = lane >> 4;
  const int b16  = lane & 15;         // MFMA col slot (batch row duplicated x16)
  const int j4   = b16 >> 2;          // lane's n-subtile j / GEMM2 ct select
  const int r4   = b16 & 3;           // lane's r within the D reg quad
  const int nph  = (w*4 + j4)*16 + q*4 + r4;   // the ONE phase this lane owns

  char* T1g = wsb;                    // 64 KiB: (pt 8, F 16) i2 frag-pairs x 64 lanes x 8 B

  // ---- LDS init: zero page only
  if (tid < 4) *(unsigned*)(smem + ZP_OFF + tid*4) = 0;

  // ---- xstage: x row bk -> bf16 B-frag chunks (linear), d>=784 zero (encoder)
  if (tid < 100) {
    const int dg = tid;
    bf16x8 fr = {0,0,0,0,0,0,0,0};
    if (dg < 98) {
      f32x4 v0 = *(const f32x4*)(x + (size_t)bk*784 + dg*8);
      f32x4 v1 = *(const f32x4*)(x + (size_t)bk*784 + dg*8 + 4);
      #pragma unroll
      for (int i = 0; i < 8; ++i) fr[i] = (short)f2bf(i < 4 ? v0[i] : v1[i-4]);
    }
    *(bf16x8*)(smem + XST_OFF + (dg << 4)) = fr;
  }

  // ---- table gen
  if (w < 8) {  // T1 i2 -> global: lane: p = w*16+b16, n = F*64 + q*16 + i
    const int p = w*16 + b16;
    for (int F = 0; F < 16; ++F) {
      const int n0 = F*64 + q*16;
      f32x4 v0 = *(const f32x4*)(xi + p*1024 + n0);
      f32x4 v1 = *(const f32x4*)(xi + p*1024 + n0 + 4);
      f32x4 v2 = *(const f32x4*)(xi + p*1024 + n0 + 8);
      f32x4 v3 = *(const f32x4*)(xi + p*1024 + n0 + 12);
      unsigned pc = 0, ps = 0;
      #pragma unroll
      for (int i = 0; i < 16; ++i) {
        float xv = (i < 4) ? v0[i] : (i < 8) ? v1[i-4] : (i < 12) ? v2[i-8] : v3[i-12];
        int uc = __float2int_rn(__cosf(xv)*1.5f + 1.5f);   // 0..3
        int us = __float2int_rn(__sinf(xv)*1.5f + 1.5f);
        const int sh = 8*(i & 3) + 2*(i >> 2);
        pc |= (unsigned)uc << sh;
        ps |= (unsigned)us << sh;
      }
      i32x2 P = {(int)pc, (int)ps};
      *(i32x2*)(T1g + (size_t)(w*16 + F)*512 + lane*8) = P;
    }
  } else {      // T2 i4 -> LDS: lane: n = ct*16+b16, p = P2*64 + q*16 + i
    const int w2 = w - 8;
    for (int f = 0; f < 16; ++f) {
      const int ct = w2*8 + (f >> 1), P2 = f & 1;
      const int n = ct*16 + b16;
      int cu[16], su[16];
      #pragma unroll
      for (int i = 0; i < 16; ++i) {
        float xv = xi[(P2*64 + q*16 + i)*1024 + n];
        su[i] = __float2int_rn(__sinf(xv)*7.0f) + 8;   // 1..15
        cu[i] = __float2int_rn(__cosf(xv)*7.0f) + 8;
      }
      unsigned pc0=0, pc1=0, ps0=0, ps1=0;
      #pragma unroll
      for (int i = 0; i < 4; ++i) {
        pc0 |= (unsigned)(cu[i]     | (cu[i+4]  << 4)) << (8*i);
        pc1 |= (unsigned)(cu[8+i]   | (cu[12+i] << 4)) << (8*i);
        ps0 |= (unsigned)(su[i]     | (su[i+4]  << 4)) << (8*i);
        ps1 |= (unsigned)(su[8+i]   | (su[12+i] << 4)) << (8*i);
      }
      i32x4 P = {(int)pc0, (int)pc1, (int)ps0, (int)ps1};
      *(i32x4*)(smem + T2L_OFF + (size_t)(ct*2 + P2)*1024 + lane*16) = P;
    }
  }
  __syncthreads();

  // ---- encoder (bf16 MFMA): B cols all duplicate row bk; lane keeps 1 phase.
  float p0, ka, pwv;
  {
    f32x4 pac[4] = {{0,0,0,0},{0,0,0,0},{0,0,0,0},{0,0,0,0}};
    for (int kt = 0; kt < 25; ++kt) {
      bf16x8 bfr = *(const bf16x8*)(smem + XST_OFF + ((kt*4 + q) << 4));
      const int d = kt*32 + q*8;
      #pragma unroll
      for (int j = 0; j < 4; ++j) {
        bf16x8 afr = {0,0,0,0,0,0,0,0};
        if (d < 784) {
          const int n = (w*4 + j)*16 + b16;
          f32x4 v0 = *(const f32x4*)(W_enc + n*784 + d);
          f32x4 v1 = *(const f32x4*)(W_enc + n*784 + d + 4);
          #pragma unroll
          for (int i = 0; i < 8; ++i) afr[i] = (short)f2bf(i < 4 ? v0[i] : v1[i-4]);
        }
        pac[j] = __builtin_amdgcn_mfma_f32_16x16x32_bf16(afr, bfr, pac[j], 0, 0, 0);
      }
    }
    f32x4 pc = (j4==0) ? pac[0] : (j4==1) ? pac[1] : (j4==2) ? pac[2] : pac[3];
    float vA = (r4==0) ? pc[0] : (r4==1) ? pc[1] : (r4==2) ? pc[2] : pc[3];
    float ph = 6.283185307179586f / (1.0f + __expf(-(vA + b_enc[nph])));
    p0 = ph; pwv = ph; ka = 0.0f;
  }

  const float dtf = 0.03125f, half = 0.015625f;
  const float sixth = (float)(0.03125/6.0);
  const float mscale = (float)(2.0 / (1024.0 * 190.5));     // BETA/N / (1.5*127)
  const float kscale = (float)(1.0 / 889.0);                // 1/(7*127)

  char* a1wr = smem + A1_OFF + nph;   // per-lane feat byte address (constant)

  for (int e = 0; e < 64; ++e) {
    float csv, snv;
    // ---- Phase A: all 64 lanes, 1 phase each; 1 cos + 1 sin byte store
    {
      snv = __sinf(pwv);
      csv = __cosf(pwv);
      *(char*)(a1wr)        = (char)(__float2int_rn(csv*127.0f));
      *(char*)(a1wr + 1024) = (char)(__float2int_rn(snv*127.0f));
    }
    __syncthreads();

    // ---- GEMM1 i8 K=64 with i2 T1 (SWAR unpack, biased +1.5); 16 MFMA/wave
    {
      const int pt = w & 7, kh = w >> 3;
      i32x4 accC = {0,0,0,0}, accS = {0,0,0,0};
      const char* t1b = T1g + (size_t)(pt*16 + kh*8)*512 + lane*8;
      const char* a1b = smem + A1_OFF + kh*512 + q*16;
      const unsigned M2 = 0x03030303u;
      #pragma unroll
      for (int i2 = 0; i2 < 8; ++i2) {
        i32x2 pk = *(const i32x2*)(t1b + (size_t)i2*512);
        unsigned pc = (unsigned)pk[0], ps = (unsigned)pk[1];
        i32x4 ca = { (int)(pc & M2), (int)((pc >> 2) & M2),
                     (int)((pc >> 4) & M2), (int)((pc >> 6) & M2) };
        i32x4 sa = { (int)(ps & M2), (int)((ps >> 2) & M2),
                     (int)((ps >> 4) & M2), (int)((ps >> 6) & M2) };
        i32x4 bc = *(const i32x4*)(a1b + i2*64);
        i32x4 bs = *(const i32x4*)(a1b + i2*64 + 1024);
        accC = __builtin_amdgcn_mfma_i32_16x16x64_i8(ca, bc, accC, 0, 0, 0);
        accS = __builtin_amdgcn_mfma_i32_16x16x64_i8(sa, bs, accS, 0, 0, 0);
      }
      if (b16 == 0) {
        i32x4 acc = accC + accS;
        *(i32x4*)(smem + MBUF_OFF + kh*528 + ((pt*16 + q*4) << 2)) = acc;
      }
    }
    __syncthreads();

    // ---- softmax (wave 0): shift-invariant to T1 bias; w i8 (x127) + exact
    // integer Sw = Sum_p w^i8_p for GEMM2 bias correction.
    if (w == 0) {
      const char* mb = smem + MBUF_OFF + lane*8;
      int a0 = *(const int*)(mb),       int_a1 = *(const int*)(mb + 4);
      int b0 = *(const int*)(mb + 528), b1 = *(const int*)(mb + 528 + 4);
      float e0 = __expf((float)(a0 + b0) * mscale);
      float e1 = __expf((float)(int_a1 + b1) * mscale);
      float s = e0 + e1;
      #pragma unroll
      for (int off = 1; off < 64; off <<= 1) s += __shfl_xor(s, off, 64);
      const float inv = 127.0f / s;
      int w0 = __float2int_rn(e0 * inv);
      int w1 = __float2int_rn(e1 * inv);
      *(unsigned short*)(smem + W_OFF + lane*2) =
          (unsigned short)((w0 & 255) | (w1 << 8));
      int sw = w0 + w1;
      #pragma unroll
      for (int off = 1; off < 64; off <<= 1) sw += __shfl_xor(sw, off, 64);
      if (lane == 0) *(int*)(smem + W_OFF + 128) = sw;
    }
    __syncthreads();

    // ---- GEMM2 (i4 T2 from LDS, all waves) + RK4: 16 MFMA/wave; bias 8*Sw
    // subtracted exactly; cached trig.
    {
      const float swt = tc.s[e], cwt = tc.c[e];
      const int st = e & 3;
      i32x4 wf0 = *(const i32x4*)(smem + W_OFF + q*16);
      i32x4 wf1 = *(const i32x4*)(smem + W_OFF + 64 + q*16);
      const int bias8 = 8 * (*(const int*)(smem + W_OFF + 128));
      i32x4 aC[4] = {{0,0,0,0},{0,0,0,0},{0,0,0,0},{0,0,0,0}};
      i32x4 aS[4] = {{0,0,0,0},{0,0,0,0},{0,0,0,0},{0,0,0,0}};
      const char* t2b = smem + T2L_OFF + (size_t)(w*8)*1024 + lane*16;
      const unsigned M = 0x0F0F0F0Fu;
      #pragma unroll
      for (int c = 0; c < 4; ++c)
        #pragma unroll
        for (int P2 = 0; P2 < 2; ++P2) {
          i32x4 pk = *(const i32x4*)(t2b + (size_t)(c*2 + P2)*1024);
          i32x4 ct_ = { (int)((unsigned)pk[0] & M), (int)(((unsigned)pk[0] >> 4) & M),
                        (int)((unsigned)pk[1] & M), (int)(((unsigned)pk[1] >> 4) & M) };
          i32x4 st_ = { (int)((unsigned)pk[2] & M), (int)(((unsigned)pk[2] >> 4) & M),
                        (int)((unsigned)pk[3] & M), (int)(((unsigned)pk[3] >> 4) & M) };
          i32x4 wf = P2 ? wf1 : wf0;
          aC[c] = __builtin_amdgcn_mfma_i32_16x16x64_i8(ct_, wf, aC[c], 0, 0, 0);
          aS[c] = __builtin_amdgcn_mfma_i32_16x16x64_i8(st_, wf, aS[c], 0, 0, 0);
        }
      i32x4 c4 = (j4==0) ? aC[0] : (j4==1) ? aC[1] : (j4==2) ? aC[2] : aC[3];
      i32x4 s4 = (j4==0) ? aS[0] : (j4==1) ? aS[1] : (j4==2) ? aS[2] : aS[3];
      int iC = (r4==0) ? c4[0] : (r4==1) ? c4[1] : (r4==2) ? c4[2] : c4[3];
      int iS = (r4==0) ? s4[0] : (r4==1) ? s4[1] : (r4==2) ? s4[2] : s4[3];
      float vC = (float)(iC - bias8);
      float vS = (float)(iS - bias8);
      float kv = (snv*vC - csv*vS) * kscale
               + 0.08f*(swt*csv - cwt*snv);           // A*sin(wt - phi)
      if (st == 0)      { ka  = kv;           pwv = p0 + kv*half; }
      else if (st == 1) { ka += 2.0f*kv;      pwv = p0 + kv*half; }
      else if (st == 2) { ka += 2.0f*kv;      pwv = p0 + kv*dtf;  }
      else { ka += kv; p0 += ka*sixth; pwv = p0; }
    }
  }

  // ---- epilogue (bf16 MFMA): out = [cos phiT, sin phiT] @ W_out^T + b_out
  __syncthreads();
  {
    *(unsigned short*)(smem + A1_OFF + nph*2)        = f2bf(__cosf(p0));
    *(unsigned short*)(smem + A1_OFF + 2048 + nph*2) = f2bf(__sinf(p0));
  }
  __syncthreads();
  {  // D[cl][col] partial over this wave's 4 ktiles; A = W_out rows (cl<10, pad 0)
    f32x4 acc = {0.f, 0.f, 0.f, 0.f};
    #pragma unroll
    for (int i2 = 0; i2 < 4; ++i2) {
      const int kt = w*4 + i2;
      const int k = kt*32 + q*8;
      bf16x8 afr = {0,0,0,0,0,0,0,0};
      if (b16 < 10) {
        f32x4 v0 = *(const f32x4*)(W_out + b16*2048 + k);
        f32x4 v1 = *(const f32x4*)(W_out + b16*2048 + k + 4);
        #pragma unroll
        for (int i = 0; i < 8; ++i) afr[i] = (short)f2bf(i < 4 ? v0[i] : v1[i-4]);
      }
      const char* baddr = (b16 == 0)
          ? (smem + A1_OFF + ((kt*4 + q) << 4))
          : (smem + ZP_OFF);
      bf16x8 bfr = *(const bf16x8*)baddr;
      acc = __builtin_amdgcn_mfma_f32_16x16x32_bf16(afr, bfr, acc, 0, 0, 0);
    }
    *(f32x4*)(smem + RED_OFF + ((w*64 + lane) << 4)) = acc;
  }
  __syncthreads();
  if (tid < 64) {   // reduce 16 wave-partials; lane: col = tid&15, cl = (tid>>4)*4+r
    f32x4 s = {0.f, 0.f, 0.f, 0.f};
    #pragma unroll
    for (int w2 = 0; w2 < 16; ++w2)
      s += *(const f32x4*)(smem + RED_OFF + ((w2*64 + tid) << 4));
    const int b = tid & 15, q2 = tid >> 4;
    if (b == 0) {
      #pragma unroll
      for (int r = 0; r < 4; ++r) {
        const int cl = q2*4 + r;
        if (cl < 10)
          dout[(size_t)bk*10 + cl] = s[r] + b_out[cl];
      }
    }
  }
}

extern "C" void kernel_launch(void* const* d_in, const int* in_sizes, int n_in,
                              void* d_out, int out_size, void* d_ws, size_t ws_size,
                              hipStream_t stream) {
  (void)in_sizes; (void)n_in; (void)ws_size; (void)out_size;
  const float* x     = (const float*)d_in[0];
  const float* W_enc = (const float*)d_in[1];
  const float* b_enc = (const float*)d_in[2];
  const float* xi    = (const float*)d_in[3];
  const float* W_out = (const float*)d_in[4];
  const float* b_out = (const float*)d_in[5];
  float* out = (float*)d_out;
  char* wsb = (char*)d_ws;   // T1 i2 64K @0; rewritten per launch (T2 LDS-only)

  TCons tc;
  const double OME = 2.0 * 3.14159265358979323846 * 200.0;
  const double dtd = 0.03125;
  const double co[4] = {0.0, 0.5, 0.5, 1.0};
  for (int e = 0; e < 64; ++e) {
    double t = ((double)(e >> 2) + co[e & 3]) * dtd;
    tc.s[e] = (float)sin(OME * t);
    tc.c[e] = (float)cos(OME * t);
  }

  phasenn_kernel<<<dim3(256), dim3(1024), 0, stream>>>(
      x, W_enc, b_enc, xi, W_out, b_out, out, wsb, tc);
}